// Round 5
// baseline (530.041 us; speedup 1.0000x reference)
//
#include <hip/hip_runtime.h>
#include <math.h>

// Problem constants (B=16, N=M=2048, eps=0.05, 10 sinkhorn iters)
#define NPTS    2048
#define NBATCH  16
#define THREADS 256
#define BLOCKS_PER_BATCH 64     // 1024 total blocks = 4/CU x 256 CU exactly
#define ROWS_PER_BLOCK   32
#define ROWS_PER_WAVE    8

static constexpr float KEPS_L  = 28.853900817779268f;   // log2(e)/eps
static constexpr float LOGMU_L = -11.0f;                 // log_mu*log2(e) = -log2(2048), exact
static constexpr float EPS_LN2 = 0.03465735902799727f;   // eps*ln(2)
static constexpr float K2      = 832.5475918208669f;     // KEPS_L^2
static constexpr float INV_K2  = 1.2011331562368226e-3f; // 1/K2
static constexpr float CLAMP2  = 8.325475918208669e-10f; // K2 * 1e-12

// Pack both point clouds as K-scaled float4 {Kx,Ky,Kz,|Kp|^2}.
// Scaled domain: d2' = K^2*d2, so exp term = exp2(-sqrt(d2')) with no multiply.
__global__ void pack_pts(const float* __restrict__ a, const float* __restrict__ b,
                         float4* __restrict__ pa, float4* __restrict__ pb) {
  int idx = blockIdx.x * blockDim.x + threadIdx.x;
  if (idx < NBATCH * NPTS) {
    float x = KEPS_L * a[3*idx], y = KEPS_L * a[3*idx+1], z = KEPS_L * a[3*idx+2];
    pa[idx] = make_float4(x, y, z, fmaf(x, x, fmaf(y, y, z*z)));
    float u = KEPS_L * b[3*idx], v = KEPS_L * b[3*idx+1], w = KEPS_L * b[3*idx+2];
    pb[idx] = make_float4(u, v, w, fmaf(u, u, fmaf(v, v, w*w)));
  }
}

// One half-iteration of log-domain Sinkhorn:
//   dualQ[j] = -eps * LSE_i[(dualR[i] - C_ij)/eps + log_mu]
// exp2-domain with per-batch shift A = max_i a_i, a_i = f_i*KEPS_L + LOGMU_L.
// LDS stages {Kx,Ky,Kz,-0.5|Kp|^2} and weight w_i = 2^(a_i - A) (<= 1).
// Inner loop per (i,row), all in scaled domain:
//   t = p.q' - 0.5|p'|^2 (3 fma), d2' = fma(-2,t,|q'|^2) (1), clamp (1),
//   VALU fast-rsqrt + 1 Newton (6), exp2 of -d2'*y (1 mul + 1 trans),
//   s += e*w (1 fma)  -> 13 VALU + 1 trans  (trans-pipe load halved vs HW sqrt).
template<bool INIT, bool CHAMFER>
__global__ __launch_bounds__(THREADS, 4)
void lse_pass(const float4* __restrict__ pR, const float4* __restrict__ pQ,
              const float* __restrict__ dualR, float* __restrict__ dualQ,
              float* __restrict__ chamPart) {
  __shared__ float4 sx[NPTS];   // 32 KB: {Kx,Ky,Kz,-0.5|Kp|^2}
  __shared__ float  sw[NPTS];   //  8 KB: 2^(a_i - A)
  // total 40960 B exactly -> 4 blocks/CU; sx doubles as reduce scratch.

  const int b    = blockIdx.x >> 6;        // batch
  const int blk  = blockIdx.x & 63;        // block within batch
  const int tid  = threadIdx.x;
  const int lane = tid & 63;
  const int wave = tid >> 6;

  const float4* __restrict__ px = pR + b * NPTS;
  float A;

  if constexpr (INIT) {
    // f == 0: a_i = LOGMU_L for all i -> A = LOGMU_L, w_i = 1
#pragma unroll
    for (int u = 0; u < 8; ++u) {
      int k = tid + u * THREADS;
      float4 p = px[k];
      sx[k] = make_float4(p.x, p.y, p.z, -0.5f * p.w);
      sw[k] = 1.0f;
    }
    A = LOGMU_L;
    __syncthreads();
  } else {
    const float* __restrict__ fb = dualR + b * NPTS;
    float av[8];
    float lm = -3.4e38f;
#pragma unroll
    for (int u = 0; u < 8; ++u) {
      int k = tid + u * THREADS;
      float a = fmaf(fb[k], KEPS_L, LOGMU_L);
      av[u] = a;
      lm = fmaxf(lm, a);
    }
#pragma unroll
    for (int off = 32; off; off >>= 1) lm = fmaxf(lm, __shfl_xor(lm, off));
    float* scratch = (float*)sx;           // sx not yet staged -> usable
    if (lane == 0) scratch[wave] = lm;
    __syncthreads();
    A = fmaxf(fmaxf(scratch[0], scratch[1]), fmaxf(scratch[2], scratch[3]));
    __syncthreads();                       // done reading scratch before staging
#pragma unroll
    for (int u = 0; u < 8; ++u) {
      int k = tid + u * THREADS;
      float4 p = px[k];
      sx[k] = make_float4(p.x, p.y, p.z, -0.5f * p.w);
      sw[k] = __builtin_amdgcn_exp2f(av[u] - A);
    }
    __syncthreads();
  }

  const float4* __restrict__ qa = pQ + b * NPTS;
  float* __restrict__ gout = dualQ + b * NPTS;
  const int j0 = blk * ROWS_PER_BLOCK + wave * ROWS_PER_WAVE;

  float4 q[ROWS_PER_WAVE];
  float  s[ROWS_PER_WAVE];
  float  m[ROWS_PER_WAVE];
#pragma unroll
  for (int r = 0; r < ROWS_PER_WAVE; ++r) {
    q[r] = qa[j0 + r];
    s[r] = 0.f;
    if constexpr (CHAMFER) m[r] = 3.4e38f;
  }

#pragma unroll 2
  for (int i = lane; i < NPTS; i += 64) {
    const float4 p  = sx[i];
    const float  wi = sw[i];
#pragma unroll
    for (int r = 0; r < ROWS_PER_WAVE; ++r) {
      float t  = fmaf(p.x, q[r].x, fmaf(p.y, q[r].y, fmaf(p.z, q[r].z, p.w)));
      float d2 = fmaxf(fmaf(-2.f, t, q[r].w), CLAMP2);   // = K^2 * d2, clamped
      if constexpr (CHAMFER) m[r] = fminf(m[r], d2);
      // VALU fast inverse sqrt (magic + 1 Newton), rel err <= ~1.8e-3
      float y0 = __int_as_float(0x5f375a86 - (__float_as_int(d2) >> 1));
      float y  = y0 * fmaf(-0.5f * d2, y0 * y0, 1.5f);
      float e  = __builtin_amdgcn_exp2f(-(d2 * y));      // = 2^(-K*sqrt(d2))
      s[r] = fmaf(e, wi, s[r]);
    }
  }

  // full-wave xor reductions (all lanes end with the result)
#pragma unroll
  for (int off = 32; off; off >>= 1) {
#pragma unroll
    for (int r = 0; r < ROWS_PER_WAVE; ++r) {
      s[r] += __shfl_xor(s[r], off);
      if constexpr (CHAMFER) m[r] = fminf(m[r], __shfl_xor(m[r], off));
    }
  }

  if (lane == 0) {
#pragma unroll
    for (int r = 0; r < ROWS_PER_WAVE; ++r)
      gout[j0 + r] = -EPS_LN2 * (A + __builtin_amdgcn_logf(fmaxf(s[r], 1e-37f)));
  }

  if constexpr (CHAMFER) {
    float chamAcc = 0.f;
#pragma unroll
    for (int r = 0; r < ROWS_PER_WAVE; ++r) chamAcc += m[r];
    chamAcc *= INV_K2;                      // back to unscaled d2
    __syncthreads();                        // everyone done with sx
    float* scratch = (float*)sx;
    if (lane == 0) scratch[wave] = chamAcc;
    __syncthreads();
    if (tid == 0)
      chamPart[blockIdx.x] = (scratch[0] + scratch[1]) + (scratch[2] + scratch[3]);
  }
}

// Stage 1: 66 blocks x 256 threads, one float4 per thread (66*256*4 = 67584
// floats = f(32768) + g(32768) + cham(2048), contiguous). Fixed-order,
// deterministic.
__global__ void final1(const float4* __restrict__ base, float* __restrict__ part) {
  __shared__ float red[4];
  const int idx = blockIdx.x * THREADS + threadIdx.x;
  float4 v = base[idx];
  float acc = (v.x + v.y) + (v.z + v.w);
#pragma unroll
  for (int off = 32; off; off >>= 1) acc += __shfl_xor(acc, off);
  const int lane = threadIdx.x & 63, wave = threadIdx.x >> 6;
  if (lane == 0) red[wave] = acc;
  __syncthreads();
  if (threadIdx.x == 0) part[blockIdx.x] = (red[0] + red[1]) + (red[2] + red[3]);
}

// Stage 2: one wave sums the 66 partials.
__global__ void final2(const float* __restrict__ part, float* __restrict__ out) {
  const int lane = threadIdx.x;
  float acc = part[lane];                       // 66 entries, lanes 0..63
  if (lane < 2) acc += part[lane + 64];
#pragma unroll
  for (int off = 32; off; off >>= 1) acc += __shfl_xor(acc, off);
  if (lane == 0) out[0] = acc;
}

extern "C" void kernel_launch(void* const* d_in, const int* in_sizes, int n_in,
                              void* d_out, int out_size, void* d_ws, size_t ws_size,
                              hipStream_t stream) {
  const float* outPts = (const float*)d_in[0];
  const float* tgtPts = (const float*)d_in[1];
  float* out = (float*)d_out;

  char* ws = (char*)d_ws;
  float4* pwA = (float4*)ws;                                  // 32768 * 16 B
  float4* pwB = (float4*)(ws + (size_t)NBATCH * NPTS * 16);   // 32768 * 16 B
  float*  f   = (float*)(ws + (size_t)2 * NBATCH * NPTS * 16);// 32768 floats
  float*  g   = f + NBATCH * NPTS;                            // 32768 floats
  float*  cham = g + NBATCH * NPTS;                           // 2048 floats
  float*  part = cham + 2048;                                 // 66 floats
  // total ws use: ~1.26 MB

  pack_pts<<<dim3(128), dim3(THREADS), 0, stream>>>(outPts, tgtPts, pwA, pwB);

  const dim3 grid(NBATCH * BLOCKS_PER_BATCH);  // 1024
  const dim3 blk(THREADS);

  // iteration 1: f==0 (INIT), fuse both chamfer directions
  lse_pass<true,  true ><<<grid, blk, 0, stream>>>(pwA, pwB, nullptr, g, cham);
  lse_pass<false, true ><<<grid, blk, 0, stream>>>(pwB, pwA, g, f, cham + 1024);
  // iterations 2..10
  for (int t = 1; t < 10; ++t) {
    lse_pass<false, false><<<grid, blk, 0, stream>>>(pwA, pwB, f, g, nullptr);
    lse_pass<false, false><<<grid, blk, 0, stream>>>(pwB, pwA, g, f, nullptr);
  }

  // emd_loss = sum(f) + sum(g) (N==M), plus chamfer partials; contiguous from f.
  final1<<<dim3(66), blk, 0, stream>>>((const float4*)f, part);
  final2<<<dim3(1), dim3(64), 0, stream>>>(part, out);
}

// Round 6
// 399.514 us; speedup vs baseline: 1.3267x; 1.3267x over previous
//
#include <hip/hip_runtime.h>
#include <math.h>

// Problem constants (B=16, N=M=2048, eps=0.05, 10 sinkhorn iters)
#define NPTS    2048
#define NBATCH  16
#define THREADS 256
#define BLOCKS_PER_BATCH 64     // 1024 total blocks = 4/CU x 256 CU exactly
#define ROWS_PER_BLOCK   32
#define ROWS_PER_WAVE    8

typedef __attribute__((ext_vector_type(2))) float f2;

static constexpr float KEPS_L  = 28.853900817779268f;   // log2(e)/eps
static constexpr float LOGMU_L = -11.0f;                 // log_mu*log2(e) = -log2(2048), exact
static constexpr float EPS_LN2 = 0.03465735902799727f;   // eps*ln(2)
static constexpr float INV_K2  = 1.2011331562368226e-3f; // 1/KEPS_L^2
static constexpr float CLAMP2  = 8.325475918208669e-10f; // KEPS_L^2 * 1e-12

// Pack both point clouds as K-scaled float4 {Kx,Ky,Kz,|Kp|^2}.
// Scaled domain: d2' = K^2*d2, so exp term = exp2(-sqrt(d2')) with no multiply.
__global__ void pack_pts(const float* __restrict__ a, const float* __restrict__ b,
                         float4* __restrict__ pa, float4* __restrict__ pb) {
  int idx = blockIdx.x * blockDim.x + threadIdx.x;
  if (idx < NBATCH * NPTS) {
    float x = KEPS_L * a[3*idx], y = KEPS_L * a[3*idx+1], z = KEPS_L * a[3*idx+2];
    pa[idx] = make_float4(x, y, z, fmaf(x, x, fmaf(y, y, z*z)));
    float u = KEPS_L * b[3*idx], v = KEPS_L * b[3*idx+1], w = KEPS_L * b[3*idx+2];
    pb[idx] = make_float4(u, v, w, fmaf(u, u, fmaf(v, v, w*w)));
  }
}

// One half-iteration of log-domain Sinkhorn:
//   dualQ[j] = -eps * LSE_i[(dualR[i] - C_ij)/eps + log_mu]
// exp2-domain with per-batch shift A = max_i a_i, a_i = f_i*KEPS_L + LOGMU_L.
// LDS stages {Kx,Ky,Kz,-0.5|Kp|^2} and weight w_i = 2^(a_i - A) (<= 1).
// Rows processed in float2 PAIRS so the dot/d2/acc VALU work emits
// v_pk_fma_f32 (packed fp32, 1 inst = 2 FMAs). Per row-pair:
//   5 pk_fma + 2 v_max (+2 v_min chamfer) + 2 sqrt + 2 exp2(neg-mod).
// HW sqrt+exp2 kept: empirically trans-issue ~16cyc but VALU-substitution
// regressed (round 5). 1-deep branchless LDS prefetch hides ds_read latency.
template<bool INIT, bool CHAMFER>
__global__ __launch_bounds__(THREADS, 4)
void lse_pass(const float4* __restrict__ pR, const float4* __restrict__ pQ,
              const float* __restrict__ dualR, float* __restrict__ dualQ,
              float* __restrict__ chamPart) {
  __shared__ float4 sx[NPTS];   // 32 KB: {Kx,Ky,Kz,-0.5|Kp|^2}
  __shared__ float  sw[NPTS];   //  8 KB: 2^(a_i - A)
  // total 40960 B exactly -> 4 blocks/CU; sx doubles as reduce scratch.

  const int b    = blockIdx.x >> 6;        // batch
  const int blk  = blockIdx.x & 63;        // block within batch
  const int tid  = threadIdx.x;
  const int lane = tid & 63;
  const int wave = tid >> 6;

  const float4* __restrict__ px = pR + b * NPTS;
  float A;

  if constexpr (INIT) {
    // f == 0: a_i = LOGMU_L for all i -> A = LOGMU_L, w_i = 1
#pragma unroll
    for (int u = 0; u < 8; ++u) {
      int k = tid + u * THREADS;
      float4 p = px[k];
      sx[k] = make_float4(p.x, p.y, p.z, -0.5f * p.w);
      sw[k] = 1.0f;
    }
    A = LOGMU_L;
    __syncthreads();
  } else {
    const float* __restrict__ fb = dualR + b * NPTS;
    float av[8];
    float lm = -3.4e38f;
#pragma unroll
    for (int u = 0; u < 8; ++u) {
      int k = tid + u * THREADS;
      float a = fmaf(fb[k], KEPS_L, LOGMU_L);
      av[u] = a;
      lm = fmaxf(lm, a);
    }
#pragma unroll
    for (int off = 32; off; off >>= 1) lm = fmaxf(lm, __shfl_xor(lm, off));
    float* scratch = (float*)sx;           // sx not yet staged -> usable
    if (lane == 0) scratch[wave] = lm;
    __syncthreads();
    A = fmaxf(fmaxf(scratch[0], scratch[1]), fmaxf(scratch[2], scratch[3]));
    __syncthreads();                       // done reading scratch before staging
#pragma unroll
    for (int u = 0; u < 8; ++u) {
      int k = tid + u * THREADS;
      float4 p = px[k];
      sx[k] = make_float4(p.x, p.y, p.z, -0.5f * p.w);
      sw[k] = __builtin_amdgcn_exp2f(av[u] - A);
    }
    __syncthreads();
  }

  const float4* __restrict__ qa = pQ + b * NPTS;
  float* __restrict__ gout = dualQ + b * NPTS;
  const int j0 = blk * ROWS_PER_BLOCK + wave * ROWS_PER_WAVE;

  // Row pairs as float2 SoA for packed-fp32 codegen
  f2 qx[4], qy[4], qz[4], qw[4], s2[4], m2[4];
#pragma unroll
  for (int rp = 0; rp < 4; ++rp) {
    float4 q0 = qa[j0 + 2*rp];
    float4 q1 = qa[j0 + 2*rp + 1];
    qx[rp] = (f2){q0.x, q1.x};
    qy[rp] = (f2){q0.y, q1.y};
    qz[rp] = (f2){q0.z, q1.z};
    qw[rp] = (f2){q0.w, q1.w};
    s2[rp] = (f2){0.f, 0.f};
    if constexpr (CHAMFER) m2[rp] = (f2){3.4e38f, 3.4e38f};
  }

  float4 p  = sx[lane];
  float  wi = sw[lane];
  for (int it = 0; it < NPTS / 64; ++it) {
    const int inext = (lane + (it + 1) * 64) & (NPTS - 1);
    const float4 pn = sx[inext];
    const float  wn = sw[inext];
    const f2 pxx = (f2){p.x, p.x};
    const f2 pyy = (f2){p.y, p.y};
    const f2 pzz = (f2){p.z, p.z};
    const f2 pww = (f2){p.w, p.w};
    const f2 wii = (f2){wi, wi};
#pragma unroll
    for (int rp = 0; rp < 4; ++rp) {
      f2 t  = __builtin_elementwise_fma(pxx, qx[rp],
              __builtin_elementwise_fma(pyy, qy[rp],
              __builtin_elementwise_fma(pzz, qz[rp], pww)));
      f2 d2 = __builtin_elementwise_fma((f2){-2.f, -2.f}, t, qw[rp]);
      d2 = __builtin_elementwise_max(d2, (f2){CLAMP2, CLAMP2});
      if constexpr (CHAMFER) m2[rp] = __builtin_elementwise_min(m2[rp], d2);
      float e0 = __builtin_amdgcn_exp2f(-__builtin_amdgcn_sqrtf(d2.x));
      float e1 = __builtin_amdgcn_exp2f(-__builtin_amdgcn_sqrtf(d2.y));
      s2[rp] = __builtin_elementwise_fma((f2){e0, e1}, wii, s2[rp]);
    }
    p = pn;
    wi = wn;
  }

  float s[ROWS_PER_WAVE], m[ROWS_PER_WAVE];
#pragma unroll
  for (int rp = 0; rp < 4; ++rp) {
    s[2*rp] = s2[rp].x;  s[2*rp+1] = s2[rp].y;
    if constexpr (CHAMFER) { m[2*rp] = m2[rp].x;  m[2*rp+1] = m2[rp].y; }
  }

  // full-wave xor reductions (all lanes end with the result)
#pragma unroll
  for (int off = 32; off; off >>= 1) {
#pragma unroll
    for (int r = 0; r < ROWS_PER_WAVE; ++r) {
      s[r] += __shfl_xor(s[r], off);
      if constexpr (CHAMFER) m[r] = fminf(m[r], __shfl_xor(m[r], off));
    }
  }

  if (lane == 0) {
#pragma unroll
    for (int r = 0; r < ROWS_PER_WAVE; ++r)
      gout[j0 + r] = -EPS_LN2 * (A + __builtin_amdgcn_logf(fmaxf(s[r], 1e-37f)));
  }

  if constexpr (CHAMFER) {
    float chamAcc = 0.f;
#pragma unroll
    for (int r = 0; r < ROWS_PER_WAVE; ++r) chamAcc += m[r];
    chamAcc *= INV_K2;                      // back to unscaled d2
    __syncthreads();                        // everyone done with sx
    float* scratch = (float*)sx;
    if (lane == 0) scratch[wave] = chamAcc;
    __syncthreads();
    if (tid == 0)
      chamPart[blockIdx.x] = (scratch[0] + scratch[1]) + (scratch[2] + scratch[3]);
  }
}

// Stage 1: 66 blocks x 256 threads, one float4 per thread (66*256*4 = 67584
// floats = f(32768) + g(32768) + cham(2048), contiguous). Fixed-order,
// deterministic.
__global__ void final1(const float4* __restrict__ base, float* __restrict__ part) {
  __shared__ float red[4];
  const int idx = blockIdx.x * THREADS + threadIdx.x;
  float4 v = base[idx];
  float acc = (v.x + v.y) + (v.z + v.w);
#pragma unroll
  for (int off = 32; off; off >>= 1) acc += __shfl_xor(acc, off);
  const int lane = threadIdx.x & 63, wave = threadIdx.x >> 6;
  if (lane == 0) red[wave] = acc;
  __syncthreads();
  if (threadIdx.x == 0) part[blockIdx.x] = (red[0] + red[1]) + (red[2] + red[3]);
}

// Stage 2: one wave sums the 66 partials.
__global__ void final2(const float* __restrict__ part, float* __restrict__ out) {
  const int lane = threadIdx.x;
  float acc = part[lane];                       // 66 entries, lanes 0..63
  if (lane < 2) acc += part[lane + 64];
#pragma unroll
  for (int off = 32; off; off >>= 1) acc += __shfl_xor(acc, off);
  if (lane == 0) out[0] = acc;
}

extern "C" void kernel_launch(void* const* d_in, const int* in_sizes, int n_in,
                              void* d_out, int out_size, void* d_ws, size_t ws_size,
                              hipStream_t stream) {
  const float* outPts = (const float*)d_in[0];
  const float* tgtPts = (const float*)d_in[1];
  float* out = (float*)d_out;

  char* ws = (char*)d_ws;
  float4* pwA = (float4*)ws;                                  // 32768 * 16 B
  float4* pwB = (float4*)(ws + (size_t)NBATCH * NPTS * 16);   // 32768 * 16 B
  float*  f   = (float*)(ws + (size_t)2 * NBATCH * NPTS * 16);// 32768 floats
  float*  g   = f + NBATCH * NPTS;                            // 32768 floats
  float*  cham = g + NBATCH * NPTS;                           // 2048 floats
  float*  part = cham + 2048;                                 // 66 floats
  // total ws use: ~1.26 MB

  pack_pts<<<dim3(128), dim3(THREADS), 0, stream>>>(outPts, tgtPts, pwA, pwB);

  const dim3 grid(NBATCH * BLOCKS_PER_BATCH);  // 1024
  const dim3 blk(THREADS);

  // iteration 1: f==0 (INIT), fuse both chamfer directions
  lse_pass<true,  true ><<<grid, blk, 0, stream>>>(pwA, pwB, nullptr, g, cham);
  lse_pass<false, true ><<<grid, blk, 0, stream>>>(pwB, pwA, g, f, cham + 1024);
  // iterations 2..10
  for (int t = 1; t < 10; ++t) {
    lse_pass<false, false><<<grid, blk, 0, stream>>>(pwA, pwB, f, g, nullptr);
    lse_pass<false, false><<<grid, blk, 0, stream>>>(pwB, pwA, g, f, nullptr);
  }

  // emd_loss = sum(f) + sum(g) (N==M), plus chamfer partials; contiguous from f.
  final1<<<dim3(66), blk, 0, stream>>>((const float4*)f, part);
  final2<<<dim3(1), dim3(64), 0, stream>>>(part, out);
}